// Round 4
// baseline (489.009 us; speedup 1.0000x reference)
//
#include <hip/hip_runtime.h>
#include <math.h>

#define DD 128            // feature dim
#define KNB 20            // neighbors per node
#define K3 384            // 3*D
#define APITCH 392        // bf16 elems/row; 784B: 16B-aligned, stride==4 mod 32 banks
#define HPITCH 136        // 272B rows: 16B-aligned, stride==4 mod 32 banks

typedef unsigned short u16;
typedef __attribute__((ext_vector_type(8))) short short8;   // 8 bf16 = 4 VGPRs
typedef __attribute__((ext_vector_type(4))) float f32x4;

// f32 -> bf16 round-to-nearest-even
static __device__ __forceinline__ u16 f2bf(float x) {
    union { float f; unsigned u; } v; v.f = x;
    unsigned r = v.u + 0x7fffu + ((v.u >> 16) & 1u);
    return (u16)(r >> 16);
}

// fast cos via v_fract + v_cos_f32 (revolutions). Abs err ~7.5e-4 at |x|~1e4,
// far below the bf16 quantization already in the AGG path (passes at 0.125).
static __device__ __forceinline__ float fcos(float x) {
    float r = x * 0.15915494309189535f;       // 1/(2*pi)
    r = __builtin_amdgcn_fractf(r);
    return __builtin_amdgcn_cosf(r);
}

static __device__ __forceinline__ void st4bf(u16* p, float4 v) {
    ushort4 s;
    s.x = f2bf(v.x); s.y = f2bf(v.y); s.z = f2bf(v.z); s.w = f2bf(v.w);
    *(ushort4*)p = s;
}

// ---------------------------------------------------------------------------
// prep: blocks 0..39 pack W1/W2 into MFMA B-fragment order (bf16);
//       block 40 computes cvec[d] = b2[d] + sum_i cos(tb[i]) * W2[(2D+i)*D+d]
// B-frag (16x16x32): lane L holds B[k0+(L>>4)*8+j][ct*16+(L&15)], j=0..7,
// 16B contiguous per lane at [ktile][ct][L][8].
// ---------------------------------------------------------------------------
__global__ __launch_bounds__(256) void prep_kernel(
    const float* __restrict__ W1, const float* __restrict__ W2,
    const float* __restrict__ tb, const float* __restrict__ b2,
    u16* __restrict__ W1p, u16* __restrict__ W2p, float* __restrict__ cvec)
{
    if (blockIdx.x == 40) {
        int d = threadIdx.x;
        if (d < DD) {
            float acc = b2[d];
            #pragma unroll 8
            for (int i = 0; i < DD; ++i)
                acc = fmaf(cosf(tb[i]), W2[(size_t)(2 * DD + i) * DD + d], acc);
            cvec[d] = acc;
        }
        return;
    }
    int t = blockIdx.x * 256 + threadIdx.x;
    if (t < 6144) {                       // W1: 12 ktiles * 8 ct * 64 lanes
        int L = t & 63;
        int ct = (t >> 6) & 7;
        int kt = t >> 9;
        int n  = ct * 16 + (L & 15);
        int kb = kt * 32 + (L >> 4) * 8;
        u16* d = W1p + (size_t)t * 8;
        #pragma unroll
        for (int j = 0; j < 8; ++j) d[j] = f2bf(W1[(size_t)(kb + j) * DD + n]);
    } else if (t < 10240) {               // W2 parts 0,1: 2 * 4 * 8 * 64
        int u = t - 6144;
        int L = u & 63;
        int ct = (u >> 6) & 7;
        int kt = (u >> 9) & 3;
        int part = u >> 11;
        int n  = ct * 16 + (L & 15);
        int kb = part * DD + kt * 32 + (L >> 4) * 8;
        u16* d = W2p + (size_t)u * 8;
        #pragma unroll
        for (int j = 0; j < 8; ++j) d[j] = f2bf(W2[(size_t)(kb + j) * DD + n]);
    }
}

// ---------------------------------------------------------------------------
// Fully fused: aggregation (gather+time-encode, bf16 into LDS A-tile) +
// H = relu(AGG@W1 + 20*b1) + out = H@W2a + NF@W2b + cvec.
// 32 nodes/block, 256 threads = 4 waves.
// LDS: As[32*392] (25088B) + overlay(8704B): index arrays during phase A,
// NF tile during phase 2. Total 33792B -> 4 blocks/CU.
// ---------------------------------------------------------------------------
__global__ __launch_bounds__(256) void fused_all(
    const float* __restrict__ nodef, const float* __restrict__ ts,
    const float* __restrict__ edgef, const int* __restrict__ neighbors,
    const int* __restrict__ edge_idxs, const float* __restrict__ edge_times,
    const float* __restrict__ tw, const float* __restrict__ tb,
    const u16* __restrict__ W1p, const u16* __restrict__ W2p,
    const float* __restrict__ b1, const float* __restrict__ cvec,
    float* __restrict__ out, int N)
{
    __shared__ __align__(16) u16 smem[32 * APITCH + 32 * HPITCH];
    u16* As   = smem;                          // AGG tile bf16; later reused as Hs
    u16* over = smem + 32 * APITCH;            // overlay: indices -> NF tile
    int*   s_nb = (int*)over;                  // [32*20]
    int*   s_eg = s_nb + 32 * KNB;             // [32*20]
    float* s_dt = (float*)(s_eg + 32 * KNB);   // [32*20]  (7680B <= 8704B)

    const int tid  = threadIdx.x;
    const int row0 = blockIdx.x * 32;

    // ---- stage indices/deltas for 32 nodes ----
    for (int i = tid; i < 32 * KNB; i += 256) {
        int nsub = i / KNB, k = i - nsub * KNB;
        int nn = row0 + nsub;
        if (nn < N) {
            s_nb[i] = neighbors[(size_t)nn * KNB + k];
            s_eg[i] = edge_idxs[(size_t)nn * KNB + k];
            s_dt[i] = ts[nn] - edge_times[(size_t)nn * KNB + k];
        } else { s_nb[i] = 0; s_eg[i] = 0; s_dt[i] = 0.f; }
    }
    __syncthreads();

    // ---- phase A: aggregation, 8 nodes per pass x 4 passes ----
    {
        const int c = tid & 31;
        const float4* nf4 = (const float4*)nodef;
        const float4* ef4 = (const float4*)edgef;
        const float4  w4  = ((const float4*)tw)[c];
        const float4  b4  = ((const float4*)tb)[c];

        #pragma unroll
        for (int g = 0; g < 4; ++g) {
            int nsub = g * 8 + (tid >> 5);
            int n = row0 + nsub;
            float4 an = make_float4(0.f, 0.f, 0.f, 0.f);
            float4 ae = an, at = an;
            const int*   nb  = s_nb + nsub * KNB;
            const int*   eg  = s_eg + nsub * KNB;
            const float* dtp = s_dt + nsub * KNB;
            int kmax = (n < N) ? KNB : 0;
            #pragma unroll 10
            for (int k = 0; k < kmax; ++k) {
                int   ni = nb[k];
                int   ei = eg[k];
                float dt = dtp[k];
                float4 nv = nf4[(size_t)ni * 32 + c];   // 512B coalesced row
                float4 ev = ef4[(size_t)ei * 32 + c];
                an.x += nv.x; an.y += nv.y; an.z += nv.z; an.w += nv.w;
                ae.x += ev.x; ae.y += ev.y; ae.z += ev.z; ae.w += ev.w;
                at.x += fcos(fmaf(dt, w4.x, b4.x));
                at.y += fcos(fmaf(dt, w4.y, b4.y));
                at.z += fcos(fmaf(dt, w4.z, b4.z));
                at.w += fcos(fmaf(dt, w4.w, b4.w));
            }
            u16* o = As + nsub * APITCH;
            st4bf(o + 4 * c,          an);
            st4bf(o + DD + 4 * c,     at);
            st4bf(o + 2 * DD + 4 * c, ae);
        }
    }
    __syncthreads();

    // ---- MFMA setup ----
    const int lane = tid & 63;
    const int wave = tid >> 6;
    const int m0     = (wave & 1) * 16;
    const int ctbase = (wave >> 1) * 4;
    const int l15  = lane & 15;
    const int quad = lane >> 4;

    // ---- phase 1: AGG @ W1 ----
    f32x4 acc[4];
    #pragma unroll
    for (int c = 0; c < 4; ++c) acc[c] = (f32x4){0.f, 0.f, 0.f, 0.f};

    const short8* W1v = (const short8*)W1p;
    for (int kt = 0; kt < 12; ++kt) {
        short8 a = *(const short8*)&As[(m0 + l15) * APITCH + kt * 32 + quad * 8];
        #pragma unroll
        for (int c = 0; c < 4; ++c) {
            short8 b = W1v[(size_t)(kt * 8 + ctbase + c) * 64 + lane];
            acc[c] = __builtin_amdgcn_mfma_f32_16x16x32_bf16(a, b, acc[c], 0, 0, 0);
        }
    }
    __syncthreads();    // all waves done reading As; indices dead too

    // ---- epilogue 1: bias+relu -> Hs (reuse As); stage NF tile into overlay ----
    u16* Hs  = As;
    u16* NFs = over;
    #pragma unroll
    for (int c = 0; c < 4; ++c) {
        int col = (ctbase + c) * 16 + l15;
        float bb = (float)KNB * b1[col];
        #pragma unroll
        for (int r = 0; r < 4; ++r) {
            float h = acc[c][r] + bb;               // C/D: col=lane&15, row=quad*4+r
            h = h > 0.f ? h : 0.f;
            Hs[(m0 + quad * 4 + r) * HPITCH + col] = f2bf(h);
        }
    }
    {
        const float4* nf4 = (const float4*)nodef;
        #pragma unroll
        for (int i = 0; i < 2; ++i) {
            int idx = tid + i * 256;                // 0..511 = 32 rows x 16 f4
            int r = idx >> 4, c = idx & 15;
            float4 v = make_float4(0.f, 0.f, 0.f, 0.f);
            int row = row0 + r;
            if (row < N) v = nf4[(size_t)row * 32 + 2 * c];  // f32 row, 8 floats
            // convert 8 f32 -> 8 bf16? need two float4s; do pairwise:
            float4 v2 = make_float4(0.f, 0.f, 0.f, 0.f);
            if (row < N) v2 = nf4[(size_t)row * 32 + 2 * c + 1];
            st4bf(&NFs[r * HPITCH + c * 8],     v);
            st4bf(&NFs[r * HPITCH + c * 8 + 4], v2);
        }
    }
    __syncthreads();

    // ---- phase 2: H@W2a + NF@W2b + cvec ----
    f32x4 acc2[4];
    #pragma unroll
    for (int c = 0; c < 4; ++c) {
        float cv = cvec[(ctbase + c) * 16 + l15];
        acc2[c] = (f32x4){cv, cv, cv, cv};
    }
    const short8* W2v = (const short8*)W2p;
    for (int kt = 0; kt < 4; ++kt) {
        short8 aH = *(const short8*)&Hs[(m0 + l15) * HPITCH + kt * 32 + quad * 8];
        #pragma unroll
        for (int c = 0; c < 4; ++c) {
            short8 b = W2v[(size_t)(kt * 8 + ctbase + c) * 64 + lane];
            acc2[c] = __builtin_amdgcn_mfma_f32_16x16x32_bf16(aH, b, acc2[c], 0, 0, 0);
        }
        short8 aN = *(const short8*)&NFs[(m0 + l15) * HPITCH + kt * 32 + quad * 8];
        #pragma unroll
        for (int c = 0; c < 4; ++c) {
            short8 b = W2v[(size_t)((4 + kt) * 8 + ctbase + c) * 64 + lane];
            acc2[c] = __builtin_amdgcn_mfma_f32_16x16x32_bf16(aN, b, acc2[c], 0, 0, 0);
        }
    }

    // ---- store ----
    #pragma unroll
    for (int c = 0; c < 4; ++c) {
        int col = (ctbase + c) * 16 + l15;
        #pragma unroll
        for (int r = 0; r < 4; ++r) {
            int row = row0 + m0 + quad * 4 + r;
            if (row < N) out[(size_t)row * DD + col] = acc2[c][r];
        }
    }
}

// ---------------------------------------------------------------------------
extern "C" void kernel_launch(void* const* d_in, const int* in_sizes, int n_in,
                              void* d_out, int out_size, void* d_ws, size_t ws_size,
                              hipStream_t stream)
{
    const float* nodef      = (const float*)d_in[0];
    const float* ts         = (const float*)d_in[1];
    const float* edgef      = (const float*)d_in[2];
    const int*   neighbors  = (const int*)d_in[3];
    const int*   edge_idxs  = (const int*)d_in[4];
    const float* edge_times = (const float*)d_in[5];
    const float* tw         = (const float*)d_in[6];
    const float* tb         = (const float*)d_in[7];
    const float* W1         = (const float*)d_in[8];
    const float* b1         = (const float*)d_in[9];
    const float* W2         = (const float*)d_in[10];
    const float* b2         = (const float*)d_in[11];
    float*       out        = (float*)d_out;

    const int N = in_sizes[1];          // 30000

    u16*   W1p  = (u16*)d_ws;                           // 12*8*64*8 bf16
    u16*   W2p  = W1p + 12 * 8 * 64 * 8;                // 2*4*8*64*8 bf16
    float* cvec = (float*)(W2p + 2 * 4 * 8 * 64 * 8);   // [128] f32

    hipLaunchKernelGGL(prep_kernel, dim3(41), dim3(256), 0, stream,
                       W1, W2, tb, b2, W1p, W2p, cvec);
    hipLaunchKernelGGL(fused_all, dim3((N + 31) / 32), dim3(256), 0, stream,
                       nodef, ts, edgef, neighbors, edge_idxs, edge_times,
                       tw, tb, W1p, W2p, b1, cvec, out, N);
}